// Round 2
// baseline (4163.521 us; speedup 1.0000x reference)
//
#include <hip/hip_runtime.h>
#include <hip/hip_bf16.h>

#define N_NODES 100000
#define N_EDGES 1600000
#define IN_DIM 48
#define OUT_DIM 128
#define K1 144   // 3*IN_DIM

typedef unsigned short u16;
typedef __attribute__((ext_vector_type(8))) short short8;
typedef __attribute__((ext_vector_type(4))) float f32x4;

// round-to-nearest-even f32 -> bf16 bits
static __device__ __forceinline__ u16 f2bf(float f) {
  unsigned u = __float_as_uint(f);
  unsigned r = (u + 0x7fffu + ((u >> 16) & 1u)) >> 16;
  return (u16)r;
}

// ---------------------------------------------------------------------------
// Stage 0: one-time weight conversion fp32 -> bf16 into workspace
// ---------------------------------------------------------------------------
__global__ __launch_bounds__(256) void prep_kernel(
    const float* __restrict__ W1, const float* __restrict__ W2,
    u16* __restrict__ W1b, u16* __restrict__ W2b)
{
  int i = blockIdx.x * 256 + threadIdx.x;
  if (i < OUT_DIM * K1) {
    W1b[i] = f2bf(W1[i]);
  } else if (i < OUT_DIM * K1 + OUT_DIM * OUT_DIM) {
    int j = i - OUT_DIM * K1;
    W2b[j] = f2bf(W2[j]);
  }
}

// ---------------------------------------------------------------------------
// Stage 1: edge scatter. 6 threads per edge, 8 dims per thread.
// mi[col] += x[row]*ea ; mo[row] += x[col]*ea   (fp32 accumulation)
// ---------------------------------------------------------------------------
__global__ __launch_bounds__(256) void scatter_kernel(
    const int* __restrict__ eidx, const float* __restrict__ x,
    const float* __restrict__ ea, float* __restrict__ mi,
    float* __restrict__ mo)
{
  int gid = blockIdx.x * 256 + threadIdx.x;
  int e = gid / 6;
  int q = gid - e * 6;          // dim group: handles dims [8q, 8q+8)
  if (e >= N_EDGES) return;
  int r = eidx[e];
  int c = eidx[N_EDGES + e];
  float w = ea[e];
  const float* xr = x + r * IN_DIM + q * 8;
  const float* xc = x + c * IN_DIM + q * 8;
  f32x4 xr0 = ((const f32x4*)xr)[0], xr1 = ((const f32x4*)xr)[1];
  f32x4 xc0 = ((const f32x4*)xc)[0], xc1 = ((const f32x4*)xc)[1];
  float* mip = mi + c * IN_DIM + q * 8;
  float* mop = mo + r * IN_DIM + q * 8;
#pragma unroll
  for (int j = 0; j < 4; ++j) {
    unsafeAtomicAdd(mip + j,     xr0[j] * w);
    unsafeAtomicAdd(mip + 4 + j, xr1[j] * w);
    unsafeAtomicAdd(mop + j,     xc0[j] * w);
    unsafeAtomicAdd(mop + 4 + j, xc1[j] * w);
  }
}

// ---------------------------------------------------------------------------
// Stage 2: fused 2-layer MLP with MFMA 16x16x32 bf16.
// M = [mi | mo | x]  (K=144, padded to 160), h = tanh(M W1^T + b1),
// out = tanh(h W2^T + b2).
// Each wave: 32 nodes (2 m-tiles). B frags read from pre-converted bf16
// weights (lane layout B[k=quad*8+j][n=lane&15] == 8 contiguous elems of
// W row n, since B = W^T).
// ---------------------------------------------------------------------------
static __device__ __forceinline__ short8 cvt8(f32x4 lo, f32x4 hi) {
  short8 r;
#pragma unroll
  for (int j = 0; j < 4; ++j) {
    r[j]     = (short)f2bf(lo[j]);
    r[4 + j] = (short)f2bf(hi[j]);
  }
  return r;
}

static __device__ __forceinline__ short8 loadM(
    const float* __restrict__ mi, const float* __restrict__ mo,
    const float* __restrict__ x, int m, int k)
{
  short8 r = {0, 0, 0, 0, 0, 0, 0, 0};
  if (k < 96) {
    const float* src = (k < 48) ? (mi + m * IN_DIM + k)
                                : (mo + m * IN_DIM + (k - 48));
    r = cvt8(((const f32x4*)src)[0], ((const f32x4*)src)[1]);
  } else if (k < K1) {
    const float* src = x + m * IN_DIM + (k - 96);
    r = cvt8(((const f32x4*)src)[0], ((const f32x4*)src)[1]);
  }
  return r;
}

__global__ __launch_bounds__(256) void mlp_kernel(
    const float* __restrict__ mi, const float* __restrict__ mo,
    const float* __restrict__ x, const u16* __restrict__ W1b,
    const float* __restrict__ b1, const u16* __restrict__ W2b,
    const float* __restrict__ b2, float* __restrict__ out)
{
  __shared__ __align__(16) u16 hbuf[4][32][136];  // +8 pad: 2-way-free banks
  const int wave = threadIdx.x >> 6;
  const int lane = threadIdx.x & 63;
  const int col  = lane & 15;
  const int quad = lane >> 4;
  const int kq   = quad * 8;
  const int nodeBase = (blockIdx.x * 4 + wave) * 32;

  const int ma0 = min(nodeBase + col,      N_NODES - 1);
  const int ma1 = min(nodeBase + 16 + col, N_NODES - 1);

  f32x4 acc[2][8];
#pragma unroll
  for (int mt = 0; mt < 2; ++mt)
#pragma unroll
    for (int nt = 0; nt < 8; ++nt) acc[mt][nt] = (f32x4){0.f, 0.f, 0.f, 0.f};

  // ---- layer 1: K = 144 (5 k-steps of 32, last half-padded) ----
#pragma unroll
  for (int ks = 0; ks < 5; ++ks) {
    const int k = ks * 32 + kq;
    short8 a0 = loadM(mi, mo, x, ma0, k);
    short8 a1 = loadM(mi, mo, x, ma1, k);
#pragma unroll
    for (int nt = 0; nt < 8; ++nt) {
      short8 b = {0, 0, 0, 0, 0, 0, 0, 0};
      if (k < K1)
        b = *(const short8*)(W1b + (nt * 16 + col) * K1 + k);
      acc[0][nt] = __builtin_amdgcn_mfma_f32_16x16x32_bf16(a0, b, acc[0][nt], 0, 0, 0);
      acc[1][nt] = __builtin_amdgcn_mfma_f32_16x16x32_bf16(a1, b, acc[1][nt], 0, 0, 0);
    }
  }

  // ---- layer-1 epilogue: bias + tanh, C-layout -> LDS (A-layout source) ----
#pragma unroll
  for (int mt = 0; mt < 2; ++mt)
#pragma unroll
    for (int nt = 0; nt < 8; ++nt) {
      const int n = nt * 16 + col;
      const float bb = b1[n];
#pragma unroll
      for (int rg = 0; rg < 4; ++rg) {
        const int rowl = mt * 16 + quad * 4 + rg;
        hbuf[wave][rowl][n] = f2bf(tanhf(acc[mt][nt][rg] + bb));
      }
    }
  __syncthreads();

  // ---- layer 2: K = 128 (4 k-steps) ----
  f32x4 acc2[2][8];
#pragma unroll
  for (int mt = 0; mt < 2; ++mt)
#pragma unroll
    for (int nt = 0; nt < 8; ++nt) acc2[mt][nt] = (f32x4){0.f, 0.f, 0.f, 0.f};

#pragma unroll
  for (int ks = 0; ks < 4; ++ks) {
    const int k = ks * 32 + kq;
    short8 a0 = *(const short8*)&hbuf[wave][col][k];
    short8 a1 = *(const short8*)&hbuf[wave][16 + col][k];
#pragma unroll
    for (int nt = 0; nt < 8; ++nt) {
      short8 b = *(const short8*)(W2b + (nt * 16 + col) * OUT_DIM + k);
      acc2[0][nt] = __builtin_amdgcn_mfma_f32_16x16x32_bf16(a0, b, acc2[0][nt], 0, 0, 0);
      acc2[1][nt] = __builtin_amdgcn_mfma_f32_16x16x32_bf16(a1, b, acc2[1][nt], 0, 0, 0);
    }
  }

  // ---- layer-2 epilogue: bias + tanh, store fp32 ----
#pragma unroll
  for (int mt = 0; mt < 2; ++mt)
#pragma unroll
    for (int nt = 0; nt < 8; ++nt) {
      const int n = nt * 16 + col;
      const float bb = b2[n];
#pragma unroll
      for (int rg = 0; rg < 4; ++rg) {
        const int node = nodeBase + mt * 16 + quad * 4 + rg;
        if (node < N_NODES)
          out[node * OUT_DIM + n] = tanhf(acc2[mt][nt][rg] + bb);
      }
    }
}

extern "C" void kernel_launch(void* const* d_in, const int* in_sizes, int n_in,
                              void* d_out, int out_size, void* d_ws, size_t ws_size,
                              hipStream_t stream) {
  const float* x   = (const float*)d_in[0];
  const int* eidx  = (const int*)d_in[1];
  const float* ea  = (const float*)d_in[2];
  const float* W1  = (const float*)d_in[3];
  const float* b1  = (const float*)d_in[4];
  const float* W2  = (const float*)d_in[5];
  const float* b2  = (const float*)d_in[6];
  float* out = (float*)d_out;

  // workspace layout: mi (fp32) | mo (fp32) | W1b (bf16) | W2b (bf16)
  float* mi = (float*)d_ws;
  float* mo = mi + (size_t)N_NODES * IN_DIM;
  u16* W1b = (u16*)(mo + (size_t)N_NODES * IN_DIM);
  u16* W2b = W1b + OUT_DIM * K1;

  // zero only the fp32 accumulation buffers (ws is poisoned 0xAA each call)
  hipMemsetAsync(d_ws, 0, (size_t)2 * N_NODES * IN_DIM * sizeof(float), stream);

  // one-time weight conversion (fully overwrites W1b/W2b regions)
  int prep_elems = OUT_DIM * K1 + OUT_DIM * OUT_DIM;
  prep_kernel<<<(prep_elems + 255) / 256, 256, 0, stream>>>(W1, W2, W1b, W2b);

  // scatter: 6 threads/edge
  scatter_kernel<<<(N_EDGES * 6) / 256, 256, 0, stream>>>(eidx, x, ea, mi, mo);

  // MLP: 128 nodes per 256-thread block
  int nblocks = (N_NODES + 127) / 128;
  mlp_kernel<<<nblocks, 256, 0, stream>>>(mi, mo, x, W1b, b1, W2b, b2, out);
}

// Round 3
// 891.700 us; speedup vs baseline: 4.6692x; 4.6692x over previous
//
#include <hip/hip_runtime.h>
#include <hip/hip_bf16.h>

#define N_NODES 100000
#define N_EDGES 1600000
#define IN_DIM 48
#define OUT_DIM 128
#define K1 144              // 3*IN_DIM
#define NSEG (2 * N_NODES)  // 200000 destination segments (node x {mi,mo})
#define NMSG (2 * N_EDGES)  // 3.2M directed messages
#define NPAD 200704         // NSEG padded to 196*1024 for the chunked scan
#define NCHUNK 196          // NPAD / 1024

typedef unsigned short u16;
typedef __attribute__((ext_vector_type(8))) short short8;
typedef __attribute__((ext_vector_type(4))) float f32x4;

// round-to-nearest-even f32 -> bf16 bits
static __device__ __forceinline__ u16 f2bf(float f) {
  unsigned u = __float_as_uint(f);
  unsigned r = (u + 0x7fffu + ((u >> 16) & 1u)) >> 16;
  return (u16)r;
}

// ---------------------------------------------------------------------------
// Stage 0: one-time weight conversion fp32 -> bf16 into workspace
// ---------------------------------------------------------------------------
__global__ __launch_bounds__(256) void prep_kernel(
    const float* __restrict__ W1, const float* __restrict__ W2,
    u16* __restrict__ W1b, u16* __restrict__ W2b)
{
  int i = blockIdx.x * 256 + threadIdx.x;
  if (i < OUT_DIM * K1) {
    W1b[i] = f2bf(W1[i]);
  } else if (i < OUT_DIM * K1 + OUT_DIM * OUT_DIM) {
    int j = i - OUT_DIM * K1;
    W2b[j] = f2bf(W2[j]);
  }
}

// ---------------------------------------------------------------------------
// CSR build: histogram -> exclusive scan -> fill
// message m: e = m>>1, dir = m&1
//   dir0: dst=col[e], src=row[e]  (mi contribution)
//   dir1: dst=row[e], src=col[e]  (mo contribution)
// segment id dst' = dst*2 + dir
// ---------------------------------------------------------------------------
__global__ __launch_bounds__(256) void hist_kernel(
    const int* __restrict__ eidx, int* __restrict__ counts)
{
  int m = blockIdx.x * 256 + threadIdx.x;
  if (m >= NMSG) return;
  int e = m >> 1, dir = m & 1;
  int row = eidx[e];
  int col = eidx[N_EDGES + e];
  int dst = dir ? row : col;
  atomicAdd(&counts[dst * 2 + dir], 1);
}

// per-chunk (1024 elems) exclusive scan; chunk totals to wgsums
__global__ __launch_bounds__(256) void scan1_kernel(
    const int* __restrict__ counts, int* __restrict__ offsets,
    int* __restrict__ wgsums)
{
  __shared__ int sh[256];
  int base = blockIdx.x * 1024;
  int4 v = ((const int4*)(counts + base))[threadIdx.x];
  int s0 = v.x, s1 = s0 + v.y, s2 = s1 + v.z, s3 = s2 + v.w;
  sh[threadIdx.x] = s3;
  __syncthreads();
#pragma unroll
  for (int off = 1; off < 256; off <<= 1) {
    int t = (threadIdx.x >= off) ? sh[threadIdx.x - off] : 0;
    __syncthreads();
    sh[threadIdx.x] += t;
    __syncthreads();
  }
  int excl = threadIdx.x ? sh[threadIdx.x - 1] : 0;
  int4 o;
  o.x = excl; o.y = excl + s0; o.z = excl + s1; o.w = excl + s2;
  ((int4*)(offsets + base))[threadIdx.x] = o;
  if (threadIdx.x == 255) wgsums[blockIdx.x] = sh[255];
}

// single-block exclusive scan of the NCHUNK chunk totals
__global__ __launch_bounds__(256) void scan2_kernel(int* __restrict__ wgsums)
{
  __shared__ int sh[256];
  int v = (threadIdx.x < NCHUNK) ? wgsums[threadIdx.x] : 0;
  sh[threadIdx.x] = v;
  __syncthreads();
#pragma unroll
  for (int off = 1; off < 256; off <<= 1) {
    int t = (threadIdx.x >= off) ? sh[threadIdx.x - off] : 0;
    __syncthreads();
    sh[threadIdx.x] += t;
    __syncthreads();
  }
  int excl = threadIdx.x ? sh[threadIdx.x - 1] : 0;
  if (threadIdx.x < NCHUNK) wgsums[threadIdx.x] = excl;
}

// add chunk prefix; also write the cursor copy used by fill
__global__ __launch_bounds__(256) void scan3_kernel(
    int* __restrict__ offsets, const int* __restrict__ wgsums,
    int* __restrict__ cursors)
{
  int add = wgsums[blockIdx.x];
  int base = blockIdx.x * 1024;
  int4 o = ((const int4*)(offsets + base))[threadIdx.x];
  o.x += add; o.y += add; o.z += add; o.w += add;
  ((int4*)(offsets + base))[threadIdx.x] = o;
  ((int4*)(cursors + base))[threadIdx.x] = o;
}

__global__ __launch_bounds__(256) void fill_kernel(
    const int* __restrict__ eidx, const float* __restrict__ ea,
    int* __restrict__ cursors, int2* __restrict__ csr)
{
  int m = blockIdx.x * 256 + threadIdx.x;
  if (m >= NMSG) return;
  int e = m >> 1, dir = m & 1;
  int row = eidx[e];
  int col = eidx[N_EDGES + e];
  int dst = dir ? row : col;
  int src = dir ? col : row;
  int slot = atomicAdd(&cursors[dst * 2 + dir], 1);
  csr[slot] = make_int2(src, __float_as_int(ea[e]));
}

// ---------------------------------------------------------------------------
// Gather: one wave per segment; lanes 0..47 = dims. fp32 register accumulate,
// single bf16 round on write (same rounding point as the old atomic path).
// Mbuf layout: [node][0..47]=mi, [48..95]=mo  (bf16)
// ---------------------------------------------------------------------------
__global__ __launch_bounds__(256) void gather_kernel(
    const int2* __restrict__ csr, const int* __restrict__ offsets,
    const float* __restrict__ x, u16* __restrict__ Mbuf)
{
  int seg = blockIdx.x * 4 + (threadIdx.x >> 6);
  int lane = threadIdx.x & 63;
  int beg = offsets[seg];
  int end = offsets[seg + 1];
  float acc = 0.f;
  for (int j = beg; j < end; ++j) {
    int2 rec = csr[j];               // wave-uniform -> scalar load
    float w = __int_as_float(rec.y);
    if (lane < IN_DIM) acc += x[rec.x * IN_DIM + lane] * w;
  }
  if (lane < IN_DIM) Mbuf[seg * IN_DIM + lane] = f2bf(acc);
  // note: seg*48 = node*96 + dir*48, exactly the [mi|mo] interleave
}

// ---------------------------------------------------------------------------
// Stage 2: fused 2-layer MLP with MFMA 16x16x32 bf16.
// ---------------------------------------------------------------------------
static __device__ __forceinline__ short8 cvt8(f32x4 lo, f32x4 hi) {
  short8 r;
#pragma unroll
  for (int j = 0; j < 4; ++j) {
    r[j]     = (short)f2bf(lo[j]);
    r[4 + j] = (short)f2bf(hi[j]);
  }
  return r;
}

static __device__ __forceinline__ short8 loadM(
    const u16* __restrict__ Mbuf, const float* __restrict__ x, int m, int k)
{
  short8 r = {0, 0, 0, 0, 0, 0, 0, 0};
  if (k < 96) {
    r = *(const short8*)(Mbuf + m * 96 + k);
  } else if (k < K1) {
    const float* src = x + m * IN_DIM + (k - 96);
    r = cvt8(((const f32x4*)src)[0], ((const f32x4*)src)[1]);
  }
  return r;
}

__global__ __launch_bounds__(256) void mlp_kernel(
    const u16* __restrict__ Mbuf, const float* __restrict__ x,
    const u16* __restrict__ W1b, const float* __restrict__ b1,
    const u16* __restrict__ W2b, const float* __restrict__ b2,
    float* __restrict__ out)
{
  __shared__ __align__(16) u16 hbuf[4][32][136];  // +8 pad: 2-way-free banks
  const int wave = threadIdx.x >> 6;
  const int lane = threadIdx.x & 63;
  const int col  = lane & 15;
  const int quad = lane >> 4;
  const int kq   = quad * 8;
  const int nodeBase = (blockIdx.x * 4 + wave) * 32;

  const int ma0 = min(nodeBase + col,      N_NODES - 1);
  const int ma1 = min(nodeBase + 16 + col, N_NODES - 1);

  f32x4 acc[2][8];
#pragma unroll
  for (int mt = 0; mt < 2; ++mt)
#pragma unroll
    for (int nt = 0; nt < 8; ++nt) acc[mt][nt] = (f32x4){0.f, 0.f, 0.f, 0.f};

  // ---- layer 1: K = 144 (5 k-steps of 32, last half-padded) ----
#pragma unroll
  for (int ks = 0; ks < 5; ++ks) {
    const int k = ks * 32 + kq;
    short8 a0 = loadM(Mbuf, x, ma0, k);
    short8 a1 = loadM(Mbuf, x, ma1, k);
#pragma unroll
    for (int nt = 0; nt < 8; ++nt) {
      short8 b = {0, 0, 0, 0, 0, 0, 0, 0};
      if (k < K1)
        b = *(const short8*)(W1b + (nt * 16 + col) * K1 + k);
      acc[0][nt] = __builtin_amdgcn_mfma_f32_16x16x32_bf16(a0, b, acc[0][nt], 0, 0, 0);
      acc[1][nt] = __builtin_amdgcn_mfma_f32_16x16x32_bf16(a1, b, acc[1][nt], 0, 0, 0);
    }
  }

  // ---- layer-1 epilogue: bias + tanh, C-layout -> LDS (A-layout source) ----
#pragma unroll
  for (int mt = 0; mt < 2; ++mt)
#pragma unroll
    for (int nt = 0; nt < 8; ++nt) {
      const int n = nt * 16 + col;
      const float bb = b1[n];
#pragma unroll
      for (int rg = 0; rg < 4; ++rg) {
        const int rowl = mt * 16 + quad * 4 + rg;
        hbuf[wave][rowl][n] = f2bf(tanhf(acc[mt][nt][rg] + bb));
      }
    }
  __syncthreads();

  // ---- layer 2: K = 128 (4 k-steps) ----
  f32x4 acc2[2][8];
#pragma unroll
  for (int mt = 0; mt < 2; ++mt)
#pragma unroll
    for (int nt = 0; nt < 8; ++nt) acc2[mt][nt] = (f32x4){0.f, 0.f, 0.f, 0.f};

#pragma unroll
  for (int ks = 0; ks < 4; ++ks) {
    const int k = ks * 32 + kq;
    short8 a0 = *(const short8*)&hbuf[wave][col][k];
    short8 a1 = *(const short8*)&hbuf[wave][16 + col][k];
#pragma unroll
    for (int nt = 0; nt < 8; ++nt) {
      short8 b = *(const short8*)(W2b + (nt * 16 + col) * OUT_DIM + k);
      acc2[0][nt] = __builtin_amdgcn_mfma_f32_16x16x32_bf16(a0, b, acc2[0][nt], 0, 0, 0);
      acc2[1][nt] = __builtin_amdgcn_mfma_f32_16x16x32_bf16(a1, b, acc2[1][nt], 0, 0, 0);
    }
  }

  // ---- layer-2 epilogue: bias + tanh, store fp32 ----
#pragma unroll
  for (int mt = 0; mt < 2; ++mt)
#pragma unroll
    for (int nt = 0; nt < 8; ++nt) {
      const int n = nt * 16 + col;
      const float bb = b2[n];
#pragma unroll
      for (int rg = 0; rg < 4; ++rg) {
        const int node = nodeBase + mt * 16 + quad * 4 + rg;
        if (node < N_NODES)
          out[node * OUT_DIM + n] = tanhf(acc2[mt][nt][rg] + bb);
      }
    }
}

extern "C" void kernel_launch(void* const* d_in, const int* in_sizes, int n_in,
                              void* d_out, int out_size, void* d_ws, size_t ws_size,
                              hipStream_t stream) {
  const float* x   = (const float*)d_in[0];
  const int* eidx  = (const int*)d_in[1];
  const float* ea  = (const float*)d_in[2];
  const float* W1  = (const float*)d_in[3];
  const float* b1  = (const float*)d_in[4];
  const float* W2  = (const float*)d_in[5];
  const float* b2  = (const float*)d_in[6];
  float* out = (float*)d_out;

  // workspace layout (all 16B-aligned):
  char* p = (char*)d_ws;
  u16* Mbuf    = (u16*)p;            p += (size_t)N_NODES * 96 * 2;   // 19.2 MB
  u16* W1b     = (u16*)p;            p += OUT_DIM * K1 * 2;           // 36,864
  u16* W2b     = (u16*)p;            p += OUT_DIM * OUT_DIM * 2;      // 32,768
  int* counts  = (int*)p;            p += (size_t)NPAD * 4;           // 802,816
  int* offsets = (int*)p;            p += (size_t)NPAD * 4;
  int* cursors = (int*)p;            p += (size_t)NPAD * 4;
  int* wgsums  = (int*)p;            p += 1024;
  int2* csr    = (int2*)p;           p += (size_t)NMSG * 8;           // 25.6 MB

  // zero the (padded) histogram counters
  hipMemsetAsync(counts, 0, (size_t)NPAD * 4, stream);

  // one-time weight conversion
  int prep_elems = OUT_DIM * K1 + OUT_DIM * OUT_DIM;
  prep_kernel<<<(prep_elems + 255) / 256, 256, 0, stream>>>(W1, W2, W1b, W2b);

  // CSR build
  hist_kernel<<<(NMSG + 255) / 256, 256, 0, stream>>>(eidx, counts);
  scan1_kernel<<<NCHUNK, 256, 0, stream>>>(counts, offsets, wgsums);
  scan2_kernel<<<1, 256, 0, stream>>>(wgsums);
  scan3_kernel<<<NCHUNK, 256, 0, stream>>>(offsets, wgsums, cursors);
  fill_kernel<<<(NMSG + 255) / 256, 256, 0, stream>>>(eidx, ea, cursors, csr);

  // gather: 4 segments per 256-thread block
  gather_kernel<<<NSEG / 4, 256, 0, stream>>>(csr, offsets, x, Mbuf);

  // MLP: 128 nodes per 256-thread block
  int nblocks = (N_NODES + 127) / 128;
  mlp_kernel<<<nblocks, 256, 0, stream>>>(Mbuf, x, W1b, b1, W2b, b2, out);
}

// Round 4
// 704.743 us; speedup vs baseline: 5.9079x; 1.2653x over previous
//
#include <hip/hip_runtime.h>
#include <hip/hip_bf16.h>

#define N_NODES 100000
#define N_EDGES 1600000
#define IN_DIM 48
#define OUT_DIM 128
#define K1 144              // 3*IN_DIM
#define NSEG (2 * N_NODES)  // 200000 destination segments (node x {mi,mo})
#define NMSG (2 * N_EDGES)  // 3.2M directed messages
#define NPAD 200704         // NSEG padded to 196*1024 for the chunked scan
#define NCHUNK 196          // NPAD / 1024

typedef unsigned short u16;
typedef __attribute__((ext_vector_type(8))) short short8;
typedef __attribute__((ext_vector_type(4))) float f32x4;

// round-to-nearest-even f32 -> bf16 bits
static __device__ __forceinline__ u16 f2bf(float f) {
  unsigned u = __float_as_uint(f);
  unsigned r = (u + 0x7fffu + ((u >> 16) & 1u)) >> 16;
  return (u16)r;
}
static __device__ __forceinline__ float bf2f(u16 u) {
  return __uint_as_float(((unsigned)u) << 16);
}

// ---------------------------------------------------------------------------
// Stage 0a: weight conversion fp32 -> bf16
// ---------------------------------------------------------------------------
__global__ __launch_bounds__(256) void prep_w_kernel(
    const float* __restrict__ W1, const float* __restrict__ W2,
    u16* __restrict__ W1b, u16* __restrict__ W2b)
{
  int i = blockIdx.x * 256 + threadIdx.x;
  if (i < OUT_DIM * K1) {
    W1b[i] = f2bf(W1[i]);
  } else if (i < OUT_DIM * K1 + OUT_DIM * OUT_DIM) {
    int j = i - OUT_DIM * K1;
    W2b[j] = f2bf(W2[j]);
  }
}

// Stage 0b: x conversion fp32 -> bf16 (compact [node][48])
__global__ __launch_bounds__(256) void prep_x_kernel(
    const float* __restrict__ x, u16* __restrict__ xb)
{
  int i = blockIdx.x * 256 + threadIdx.x;
  if (i < N_NODES * IN_DIM) xb[i] = f2bf(x[i]);
}

// ---------------------------------------------------------------------------
// CSR build: histogram -> exclusive scan -> fill   (per-EDGE threads)
//   dir0 (mi): dst=col, src=row    dir1 (mo): dst=row, src=col
// segment id = dst*2 + dir
// ---------------------------------------------------------------------------
__global__ __launch_bounds__(256) void hist_kernel(
    const int* __restrict__ eidx, int* __restrict__ counts)
{
  int e = blockIdx.x * 256 + threadIdx.x;
  if (e >= N_EDGES) return;
  int row = eidx[e];
  int col = eidx[N_EDGES + e];
  atomicAdd(&counts[col * 2 + 0], 1);
  atomicAdd(&counts[row * 2 + 1], 1);
}

// per-chunk (1024 elems) exclusive scan; chunk totals to wgsums
__global__ __launch_bounds__(256) void scan1_kernel(
    const int* __restrict__ counts, int* __restrict__ offsets,
    int* __restrict__ wgsums)
{
  __shared__ int sh[256];
  int base = blockIdx.x * 1024;
  int4 v = ((const int4*)(counts + base))[threadIdx.x];
  int s0 = v.x, s1 = s0 + v.y, s2 = s1 + v.z, s3 = s2 + v.w;
  sh[threadIdx.x] = s3;
  __syncthreads();
#pragma unroll
  for (int off = 1; off < 256; off <<= 1) {
    int t = (threadIdx.x >= off) ? sh[threadIdx.x - off] : 0;
    __syncthreads();
    sh[threadIdx.x] += t;
    __syncthreads();
  }
  int excl = threadIdx.x ? sh[threadIdx.x - 1] : 0;
  int4 o;
  o.x = excl; o.y = excl + s0; o.z = excl + s1; o.w = excl + s2;
  ((int4*)(offsets + base))[threadIdx.x] = o;
  if (threadIdx.x == 255) wgsums[blockIdx.x] = sh[255];
}

// single-block exclusive scan of the NCHUNK chunk totals
__global__ __launch_bounds__(256) void scan2_kernel(int* __restrict__ wgsums)
{
  __shared__ int sh[256];
  int v = (threadIdx.x < NCHUNK) ? wgsums[threadIdx.x] : 0;
  sh[threadIdx.x] = v;
  __syncthreads();
#pragma unroll
  for (int off = 1; off < 256; off <<= 1) {
    int t = (threadIdx.x >= off) ? sh[threadIdx.x - off] : 0;
    __syncthreads();
    sh[threadIdx.x] += t;
    __syncthreads();
  }
  int excl = threadIdx.x ? sh[threadIdx.x - 1] : 0;
  if (threadIdx.x < NCHUNK) wgsums[threadIdx.x] = excl;
}

// add chunk prefix; also write the cursor copy used by fill
__global__ __launch_bounds__(256) void scan3_kernel(
    int* __restrict__ offsets, const int* __restrict__ wgsums,
    int* __restrict__ cursors)
{
  int add = wgsums[blockIdx.x];
  int base = blockIdx.x * 1024;
  int4 o = ((const int4*)(offsets + base))[threadIdx.x];
  o.x += add; o.y += add; o.z += add; o.w += add;
  ((int4*)(offsets + base))[threadIdx.x] = o;
  ((int4*)(cursors + base))[threadIdx.x] = o;
}

__global__ __launch_bounds__(256) void fill_kernel(
    const int* __restrict__ eidx, const float* __restrict__ ea,
    int* __restrict__ cursors, int2* __restrict__ csr)
{
  int e = blockIdx.x * 256 + threadIdx.x;
  if (e >= N_EDGES) return;
  int row = eidx[e];
  int col = eidx[N_EDGES + e];
  int w = __float_as_int(ea[e]);
  int s0 = atomicAdd(&cursors[col * 2 + 0], 1);
  csr[s0] = make_int2(row, w);
  int s1 = atomicAdd(&cursors[row * 2 + 1], 1);
  csr[s1] = make_int2(col, w);
}

// ---------------------------------------------------------------------------
// Gather: one wave per segment; lanes 0..47 = dims. Unroll-4 with 4
// independent accumulators -> 4 x-row loads in flight. bf16 x input.
// Mseg layout: [node][0..47]=mi, [48..95]=mo  (bf16); seg*48 == node*96+dir*48
// ---------------------------------------------------------------------------
__global__ __launch_bounds__(256) void gather_kernel(
    const int2* __restrict__ csr, const int* __restrict__ offsets,
    const u16* __restrict__ xb, u16* __restrict__ Mseg)
{
  int seg = blockIdx.x * 4 + (threadIdx.x >> 6);
  int lane = threadIdx.x & 63;
  int beg = offsets[seg];
  int end = offsets[seg + 1];
  bool act = lane < IN_DIM;
  float a0 = 0.f, a1 = 0.f, a2 = 0.f, a3 = 0.f;
  int j = beg;
  for (; j + 4 <= end; j += 4) {
    int2 r0 = csr[j + 0];
    int2 r1 = csr[j + 1];
    int2 r2 = csr[j + 2];
    int2 r3 = csr[j + 3];
    float v0 = 0.f, v1 = 0.f, v2 = 0.f, v3 = 0.f;
    if (act) {
      v0 = bf2f(xb[r0.x * IN_DIM + lane]);
      v1 = bf2f(xb[r1.x * IN_DIM + lane]);
      v2 = bf2f(xb[r2.x * IN_DIM + lane]);
      v3 = bf2f(xb[r3.x * IN_DIM + lane]);
    }
    a0 = fmaf(v0, __int_as_float(r0.y), a0);
    a1 = fmaf(v1, __int_as_float(r1.y), a1);
    a2 = fmaf(v2, __int_as_float(r2.y), a2);
    a3 = fmaf(v3, __int_as_float(r3.y), a3);
  }
  for (; j < end; ++j) {
    int2 r = csr[j];
    float v = 0.f;
    if (act) v = bf2f(xb[r.x * IN_DIM + lane]);
    a0 = fmaf(v, __int_as_float(r.y), a0);
  }
  if (act) Mseg[seg * IN_DIM + lane] = f2bf((a0 + a1) + (a2 + a3));
}

// ---------------------------------------------------------------------------
// Stage 2: fused 2-layer MLP with MFMA 16x16x32 bf16.
// ---------------------------------------------------------------------------
static __device__ __forceinline__ short8 loadM(
    const u16* __restrict__ Mseg, const u16* __restrict__ xb, int m, int k)
{
  short8 r = {0, 0, 0, 0, 0, 0, 0, 0};
  if (k < 96) {
    r = *(const short8*)(Mseg + m * 96 + k);
  } else if (k < K1) {
    r = *(const short8*)(xb + m * IN_DIM + (k - 96));
  }
  return r;
}

__global__ __launch_bounds__(256) void mlp_kernel(
    const u16* __restrict__ Mseg, const u16* __restrict__ xb,
    const u16* __restrict__ W1b, const float* __restrict__ b1,
    const u16* __restrict__ W2b, const float* __restrict__ b2,
    float* __restrict__ out)
{
  __shared__ __align__(16) u16 hbuf[4][32][136];  // +8 pad: 2-way-free banks
  const int wave = threadIdx.x >> 6;
  const int lane = threadIdx.x & 63;
  const int col  = lane & 15;
  const int quad = lane >> 4;
  const int kq   = quad * 8;
  const int nodeBase = (blockIdx.x * 4 + wave) * 32;

  const int ma0 = min(nodeBase + col,      N_NODES - 1);
  const int ma1 = min(nodeBase + 16 + col, N_NODES - 1);

  f32x4 acc[2][8];
#pragma unroll
  for (int mt = 0; mt < 2; ++mt)
#pragma unroll
    for (int nt = 0; nt < 8; ++nt) acc[mt][nt] = (f32x4){0.f, 0.f, 0.f, 0.f};

  // ---- layer 1: K = 144 (5 k-steps of 32, last half-padded) ----
#pragma unroll
  for (int ks = 0; ks < 5; ++ks) {
    const int k = ks * 32 + kq;
    short8 a0 = loadM(Mseg, xb, ma0, k);
    short8 a1 = loadM(Mseg, xb, ma1, k);
#pragma unroll
    for (int nt = 0; nt < 8; ++nt) {
      short8 b = {0, 0, 0, 0, 0, 0, 0, 0};
      if (k < K1)
        b = *(const short8*)(W1b + (nt * 16 + col) * K1 + k);
      acc[0][nt] = __builtin_amdgcn_mfma_f32_16x16x32_bf16(a0, b, acc[0][nt], 0, 0, 0);
      acc[1][nt] = __builtin_amdgcn_mfma_f32_16x16x32_bf16(a1, b, acc[1][nt], 0, 0, 0);
    }
  }

  // ---- layer-1 epilogue: bias + tanh, C-layout -> LDS (A-layout source) ----
#pragma unroll
  for (int mt = 0; mt < 2; ++mt)
#pragma unroll
    for (int nt = 0; nt < 8; ++nt) {
      const int n = nt * 16 + col;
      const float bb = b1[n];
#pragma unroll
      for (int rg = 0; rg < 4; ++rg) {
        const int rowl = mt * 16 + quad * 4 + rg;
        hbuf[wave][rowl][n] = f2bf(tanhf(acc[mt][nt][rg] + bb));
      }
    }
  __syncthreads();

  // ---- layer 2: K = 128 (4 k-steps) ----
  f32x4 acc2[2][8];
#pragma unroll
  for (int mt = 0; mt < 2; ++mt)
#pragma unroll
    for (int nt = 0; nt < 8; ++nt) acc2[mt][nt] = (f32x4){0.f, 0.f, 0.f, 0.f};

#pragma unroll
  for (int ks = 0; ks < 4; ++ks) {
    const int k = ks * 32 + kq;
    short8 a0 = *(const short8*)&hbuf[wave][col][k];
    short8 a1 = *(const short8*)&hbuf[wave][16 + col][k];
#pragma unroll
    for (int nt = 0; nt < 8; ++nt) {
      short8 b = *(const short8*)(W2b + (nt * 16 + col) * OUT_DIM + k);
      acc2[0][nt] = __builtin_amdgcn_mfma_f32_16x16x32_bf16(a0, b, acc2[0][nt], 0, 0, 0);
      acc2[1][nt] = __builtin_amdgcn_mfma_f32_16x16x32_bf16(a1, b, acc2[1][nt], 0, 0, 0);
    }
  }

  // ---- layer-2 epilogue: bias + tanh, store fp32 ----
#pragma unroll
  for (int mt = 0; mt < 2; ++mt)
#pragma unroll
    for (int nt = 0; nt < 8; ++nt) {
      const int n = nt * 16 + col;
      const float bb = b2[n];
#pragma unroll
      for (int rg = 0; rg < 4; ++rg) {
        const int node = nodeBase + mt * 16 + quad * 4 + rg;
        if (node < N_NODES)
          out[node * OUT_DIM + n] = tanhf(acc2[mt][nt][rg] + bb);
      }
    }
}

extern "C" void kernel_launch(void* const* d_in, const int* in_sizes, int n_in,
                              void* d_out, int out_size, void* d_ws, size_t ws_size,
                              hipStream_t stream) {
  const float* x   = (const float*)d_in[0];
  const int* eidx  = (const int*)d_in[1];
  const float* ea  = (const float*)d_in[2];
  const float* W1  = (const float*)d_in[3];
  const float* b1  = (const float*)d_in[4];
  const float* W2  = (const float*)d_in[5];
  const float* b2  = (const float*)d_in[6];
  float* out = (float*)d_out;

  // workspace layout (all 16B-aligned):
  char* p = (char*)d_ws;
  u16* Mseg    = (u16*)p;            p += (size_t)N_NODES * 96 * 2;   // 19.2 MB
  u16* xb      = (u16*)p;            p += (size_t)N_NODES * IN_DIM * 2; // 9.6 MB
  u16* W1b     = (u16*)p;            p += OUT_DIM * K1 * 2;
  u16* W2b     = (u16*)p;            p += OUT_DIM * OUT_DIM * 2;
  int* counts  = (int*)p;            p += (size_t)NPAD * 4;
  int* offsets = (int*)p;            p += (size_t)NPAD * 4;
  int* cursors = (int*)p;            p += (size_t)NPAD * 4;
  int* wgsums  = (int*)p;            p += 1024;
  int2* csr    = (int2*)p;           p += (size_t)NMSG * 8;           // 25.6 MB

  // zero the (padded) histogram counters
  hipMemsetAsync(counts, 0, (size_t)NPAD * 4, stream);

  // conversions
  int prep_elems = OUT_DIM * K1 + OUT_DIM * OUT_DIM;
  prep_w_kernel<<<(prep_elems + 255) / 256, 256, 0, stream>>>(W1, W2, W1b, W2b);
  prep_x_kernel<<<(N_NODES * IN_DIM + 255) / 256, 256, 0, stream>>>(x, xb);

  // CSR build (per-edge threads)
  hist_kernel<<<(N_EDGES + 255) / 256, 256, 0, stream>>>(eidx, counts);
  scan1_kernel<<<NCHUNK, 256, 0, stream>>>(counts, offsets, wgsums);
  scan2_kernel<<<1, 256, 0, stream>>>(wgsums);
  scan3_kernel<<<NCHUNK, 256, 0, stream>>>(offsets, wgsums, cursors);
  fill_kernel<<<(N_EDGES + 255) / 256, 256, 0, stream>>>(eidx, ea, cursors, csr);

  // gather: 4 segments per 256-thread block
  gather_kernel<<<NSEG / 4, 256, 0, stream>>>(csr, offsets, xb, Mseg);

  // MLP: 128 nodes per 256-thread block
  int nblocks = (N_NODES + 127) / 128;
  mlp_kernel<<<nblocks, 256, 0, stream>>>(Mseg, xb, W1b, b1, W2b, b2, out);
}